// Round 9
// baseline (314.420 us; speedup 1.0000x reference)
//
#include <hip/hip_runtime.h>
#include <math.h>

#define N_NODES 10000
#define N_EDGES 160000
#define G_SEG 16
#define ZDIM 10
#define KDIM 64
#define NBESS 8
#define HIDR 16
#define RMAXF 5.0f
#define AVG_NEI_F 16.0f
#define TBINS 256

__device__ __forceinline__ float siluf(float x){ float s = 1.0f/(1.0f+expf(-x)); return x*s; }
__device__ __forceinline__ float dsiluf(float x){ float s = 1.0f/(1.0f+expf(-x)); return s*(1.0f + x*(1.0f-s)); }

__device__ __forceinline__ float waveReduce(float v){
  for (int off = 32; off > 0; off >>= 1) v += __shfl_down(v, off);
  return v;
}

// decode from r (CSR slots hold r; padding holds -1)
__device__ __forceinline__ void r_decode(float r, int& b, float& fr, float& wm){
  wm = (r >= 0.f) ? 1.f : 0.f;
  float tp = fmaxf(r, 0.f) * (TBINS / RMAXF);
  b = (int)tp; if (b > TBINS-1) b = TBINS-1;
  fr = tp - (float)b;
}

// ---------------- merged setup ----------------
__global__ __launch_bounds__(256) void k_setup(
    const float* We, const float* Wup, const float* Wsc,
    const float* Wout, const float* Wmix,
    const float* Wr1,
    const float* attrs, const float* aE,
    float* M0, float* Msc0,
    float* WoT0, float* WoT1, float* WmixT0, float* WupT1,
    float* P1, float* Qtab,
    int* z_buf, float* e_node){
  int blk = blockIdx.x, tid = threadIdx.x;
  const float* Wmix1 = Wmix + KDIM*KDIM;
  const float* Wsc1  = Wsc + ZDIM*KDIM*KDIM;
  if (blk < 5){
    int idx = blk*256 + tid;
    if (idx < 1280){
      int which = idx >= 640;
      int t = which ? idx - 640 : idx;
      int z = t >> 6, j = t & 63;
      float acc = 0.f;
      if (!which){
        #pragma unroll 8
        for (int k = 0; k < KDIM; k++) acc += We[z*KDIM + k] * Wup[k*KDIM + j];
        M0[z*KDIM + j] = acc;
      } else {
        #pragma unroll 8
        for (int k = 0; k < KDIM; k++) acc += We[z*KDIM + k] * Wsc[(z*KDIM + k)*KDIM + j];
        Msc0[z*KDIM + j] = acc;
      }
    }
  } else if (blk < 69){
    int t = (blk-5)*256 + tid;   // 0..16383
    int arr = t >> 12;
    int rem = t & 4095;
    int j = rem >> 6, k = rem & 63;
    float v; float* dst;
    switch(arr){
      case 0: v = Wout[k*KDIM + j];                 dst = WoT0;   break;
      case 1: v = Wout[3*KDIM*KDIM + k*KDIM + j];   dst = WoT1;   break;
      case 2: v = Wmix[k*KDIM + j];                 dst = WmixT0; break;
      default:v = Wup[KDIM*KDIM + k*KDIM + j];      dst = WupT1;  break;
    }
    dst[rem] = v;
  } else if (blk < 73){
    int t = (blk-69)*256 + tid;  // 0..1023
    int h = t >> 6, k = t & 63;
    float acc = 0.f;
    #pragma unroll 8
    for (int j = 0; j < KDIM; j++) acc += Wr1[j*HIDR + h] * Wmix1[k*KDIM + j];
    P1[h*KDIM + k] = acc;
  } else if (blk < 113){
    int t = (blk-73)*256 + tid;  // 0..10239
    int z = t >> 10;
    int rem = t & 1023;
    int h = rem >> 6, k = rem & 63;
    float acc = 0.f;
    #pragma unroll 8
    for (int j = 0; j < KDIM; j++) acc += Wr1[j*HIDR + h] * Wsc1[(z*KDIM + k)*KDIM + j];
    Qtab[(z*HIDR + h)*KDIM + k] = acc;
  } else {
    int n = (blk-113)*256 + tid;
    if (n < N_NODES){
      int z = 0;
      for (int i = 1; i < ZDIM; i++) if (attrs[n*ZDIM+i] > 0.5f) z = i;
      z_buf[n] = z;
      e_node[n] = aE[z];
    }
  }
}

// edge geometry + packed edge meta + CSR degree counting (live edges only)
__global__ __launch_bounds__(256) void k_edge_setup(const float* pos, const float* shifts, const int* ei,
                                                    const int* z_buf,
                                                    float4* evec, int4* emeta,
                                                    int* cnt_r, int* cnt_s){
  int e = blockIdx.x*256 + threadIdx.x;
  int s = ei[e], rcv = ei[N_EDGES + e];
  float dx = pos[rcv*3+0] - pos[s*3+0] + shifts[e*3+0];
  float dy = pos[rcv*3+1] - pos[s*3+1] + shifts[e*3+1];
  float dz = pos[rcv*3+2] - pos[s*3+2] + shifts[e*3+2];
  float r = sqrtf(dx*dx + dy*dy + dz*dz + 1e-9f);
  evec[e] = make_float4(dx, dy, dz, r);
  emeta[e] = make_int4(__float_as_int(r), s, rcv, z_buf[s]);
  if (r < RMAXF){
    atomicAdd(&cnt_s[s], 1);
    atomicAdd(&cnt_r[rcv], 1);
  }
}

__global__ __launch_bounds__(1024) void k_scan(const int* cnt_r, int* ptr_r, int* cur_r,
                                               const int* cnt_s, int* ptr_s, int* cur_s){
  __shared__ int part[1024];
  int tid = threadIdx.x;
  const int* cnt = blockIdx.x ? cnt_s : cnt_r;
  int* ptr = blockIdx.x ? ptr_s : ptr_r;
  int* cur = blockIdx.x ? cur_s : cur_r;
  const int per = 10;
  int start = tid*per;
  int s = 0;
  for (int t = 0; t < per; t++){ int i = start + t; if (i < N_NODES) s += cnt[i]; }
  part[tid] = s; __syncthreads();
  for (int d = 1; d < 1024; d <<= 1){
    int v = (tid >= d) ? part[tid-d] : 0;
    __syncthreads();
    part[tid] += v;
    __syncthreads();
  }
  int run = part[tid] - s;
  for (int t = 0; t < per; t++){
    int i = start + t;
    if (i < N_NODES){ ptr[i] = run; cur[i] = run; run += cnt[i]; }
  }
  if (tid == 1023) ptr[N_NODES] = part[1023];
}

__global__ __launch_bounds__(256) void k_fill(const int4* emeta, int* cur_r, int* cur_s,
                                              int4* pr_pack, int4* ps_pack){
  int e = blockIdx.x*256 + threadIdx.x;
  int4 m = emeta[e];            // {r_bits, snd, rcv, ez}
  float r = __int_as_float(m.x);
  if (r >= RMAXF) return;
  int p = atomicAdd(&cur_s[m.y], 1);
  ps_pack[p] = make_int4(m.x, m.z, e, 0);          // {r, rcv, eid}
  int p2 = atomicAdd(&cur_r[m.z], 1);
  pr_pack[p2] = make_int4(m.x, m.y, m.w, e);       // {r, snd, ez, eid}
}

// ---------------- radial-MLP tables ----------------
__global__ __launch_bounds__(64) void k_table(const float* R1g, const float* R2g,
                                              const float* R3g, const float* R4g,
                                              float2* Ft2_0, float2* Ft2_1, float* dF4f){
  int t = blockIdx.x, j = threadIdx.x;
  __shared__ float efs[NBESS], defs[NBESS];
  __shared__ float xs[KDIM], dxs[KDIM];
  if (j < NBESS){
    double r = (double)t * (double)RMAXF / (double)TBINS;
    double w = (double)(j+1) * M_PI / (double)RMAXF;
    double c = sqrt(2.0 / (double)RMAXF);
    double bess, dbess;
    if (r < 1e-12){ bess = c*w; dbess = 0.0; }
    else {
      double sw = sin(w*r), cw = cos(w*r);
      bess = c*sw/r;
      dbess = c*(w*cw*r - sw)/(r*r);
    }
    double xx = r / (double)RMAXF;
    double f = 0.0, df = 0.0;
    if (xx < 1.0){
      double x2 = xx*xx, x4 = x2*x2, x5 = x4*xx, x6 = x5*xx, x7 = x6*xx;
      f = 1.0 - 21.0*x5 + 35.0*x6 - 15.0*x7;
      df = (-105.0*x4 + 210.0*x5 - 105.0*x6) / (double)RMAXF;
    }
    efs[j]  = (float)(bess*f);
    defs[j] = (float)(dbess*f + bess*df);
  }
  __syncthreads();
  for (int i = 0; i < 2; i++){
    const float* R1 = R1g + i*NBESS*KDIM;
    const float* R2 = R2g + i*KDIM*KDIM;
    const float* R3 = R3g + i*KDIM*KDIM;
    const float* R4 = R4g + i*KDIM*KDIM;
    float z = 0.f, dz = 0.f;
    for (int b = 0; b < NBESS; b++){ float w = R1[b*KDIM+j]; z += efs[b]*w; dz += defs[b]*w; }
    float v = siluf(z), dv = dsiluf(z)*dz;
    xs[j] = v; dxs[j] = dv; __syncthreads();
    z = 0.f; dz = 0.f;
    for (int k = 0; k < KDIM; k++){ float w = R2[k*KDIM+j]; z += xs[k]*w; dz += dxs[k]*w; }
    v = siluf(z); dv = dsiluf(z)*dz; __syncthreads();
    xs[j] = v; dxs[j] = dv; __syncthreads();
    z = 0.f; dz = 0.f;
    for (int k = 0; k < KDIM; k++){ float w = R3[k*KDIM+j]; z += xs[k]*w; dz += dxs[k]*w; }
    v = siluf(z); dv = dsiluf(z)*dz; __syncthreads();
    xs[j] = v; dxs[j] = dv; __syncthreads();
    z = 0.f; dz = 0.f;
    for (int k = 0; k < KDIM; k++){ float w = R4[k*KDIM+j]; z += xs[k]*w; dz += dxs[k]*w; }
    float2* Ft  = i ? Ft2_1 : Ft2_0;
    Ft[t*KDIM+j].x = z;  if (t > 0) Ft[(t-1)*KDIM+j].y = z;
    dF4f[(t*KDIM+j)*4 + 2*i] = dz;
    if (t > 0) dF4f[((t-1)*KDIM+j)*4 + 2*i + 1] = dz;
    __syncthreads();
  }
}

// 8-edge-deep gather step (16 loads in flight)
#define GATHER8(IDXSRC, ROWPTR) \
    for (; i + 8 <= m; i += 8){ \
      float r0_ = __shfl(r_l, i),   r1_ = __shfl(r_l, i+1); \
      float r2_ = __shfl(r_l, i+2), r3_ = __shfl(r_l, i+3); \
      float r4_ = __shfl(r_l, i+4), r5_ = __shfl(r_l, i+5); \
      float r6_ = __shfl(r_l, i+6), r7_ = __shfl(r_l, i+7); \
      int s0 = __shfl(IDXSRC, i),   s1 = __shfl(IDXSRC, i+1); \
      int s2 = __shfl(IDXSRC, i+2), s3 = __shfl(IDXSRC, i+3); \
      int s4 = __shfl(IDXSRC, i+4), s5 = __shfl(IDXSRC, i+5); \
      int s6 = __shfl(IDXSRC, i+6), s7 = __shfl(IDXSRC, i+7); \
      int b0,b1,b2,b3,b4,b5,b6,b7; float f0,f1,f2,f3,f4,f5,f6,f7, w0,w1,w2,w3,w4,w5,w6,w7; \
      r_decode(r0_,b0,f0,w0); r_decode(r1_,b1,f1,w1); r_decode(r2_,b2,f2,w2); r_decode(r3_,b3,f3,w3); \
      r_decode(r4_,b4,f4,w4); r_decode(r5_,b5,f5,w5); r_decode(r6_,b6,f6,w6); r_decode(r7_,b7,f7,w7); \
      float2 F0 = Ft2[b0*KDIM + lane]; float h0_ = ROWPTR[s0*KDIM + lane]; \
      float2 F1 = Ft2[b1*KDIM + lane]; float h1_ = ROWPTR[s1*KDIM + lane]; \
      float2 F2 = Ft2[b2*KDIM + lane]; float h2_ = ROWPTR[s2*KDIM + lane]; \
      float2 F3 = Ft2[b3*KDIM + lane]; float h3_ = ROWPTR[s3*KDIM + lane]; \
      float2 F4 = Ft2[b4*KDIM + lane]; float h4_ = ROWPTR[s4*KDIM + lane]; \
      float2 F5 = Ft2[b5*KDIM + lane]; float h5_ = ROWPTR[s5*KDIM + lane]; \
      float2 F6 = Ft2[b6*KDIM + lane]; float h6_ = ROWPTR[s6*KDIM + lane]; \
      float2 F7 = Ft2[b7*KDIM + lane]; float h7_ = ROWPTR[s7*KDIM + lane]; \
      acc0 += w0*(F0.x + f0*(F0.y-F0.x))*h0_; acc1 += w1*(F1.x + f1*(F1.y-F1.x))*h1_; \
      acc2 += w2*(F2.x + f2*(F2.y-F2.x))*h2_; acc3 += w3*(F3.x + f3*(F3.y-F3.x))*h3_; \
      acc0 += w4*(F4.x + f4*(F4.y-F4.x))*h4_; acc1 += w5*(F5.x + f5*(F5.y-F5.x))*h5_; \
      acc2 += w6*(F6.x + f6*(F6.y-F6.x))*h6_; acc3 += w7*(F7.x + f7*(F7.y-F7.x))*h7_; \
    } \
    for (; i < m; i++){ \
      float r0_ = __shfl(r_l, i); \
      int s0 = __shfl(IDXSRC, i); \
      int b0; float f0, w0; \
      r_decode(r0_, b0, f0, w0); \
      float2 F0 = Ft2[b0*KDIM + lane]; float h0_ = ROWPTR[s0*KDIM + lane]; \
      acc0 += w0*(F0.x + f0*(F0.y-F0.x))*h0_; \
    }

// ---------------- layer-0 forward (M0-table gather) + epilogue + h1/sc1 ----------------
__global__ __launch_bounds__(256) void k_layer0_fwd(
    const int* z_buf, const int* ptr_r, const int4* pr_pack,
    const float2* Ft2, const float* M0,
    const float* Wout0, const float* theta0, const float* Wmix0,
    const float* Msc0, const float* w_read0,
    const float* Wup1, const float* Wsc1,
    float* A0_out, float* h1, float* sc1, float* e_node){
  __shared__ float lds[4][KDIM];
  int tid = threadIdx.x;
  int w = tid >> 6, lane = tid & 63;
  int node = blockIdx.x*4 + w;
  int z = z_buf[node];
  int beg = ptr_r[node], end = ptr_r[node+1];
  int deg = end - beg;
  float acc0 = 0.f, acc1 = 0.f, acc2 = 0.f, acc3 = 0.f;
  for (int base = 0; base < deg; base += 64){
    int m = min(64, deg - base);
    float r_l = -1.f; int sz_l = 0;
    if (lane < m){
      int4 pk = pr_pack[beg + base + lane];   // {r, snd, ez, eid}
      r_l = __int_as_float(pk.x);
      sz_l = pk.z;
    }
    int i = 0;
    GATHER8(sz_l, M0)
  }
  float acc = ((acc0 + acc1) + (acc2 + acc3)) * (1.0f/AVG_NEI_F);
  lds[w][lane] = acc;
  __syncthreads();
  float a0 = 0.f;
  #pragma unroll 4
  for (int k = 0; k < KDIM; k++) a0 += lds[w][k] * Wout0[k*KDIM + lane];
  A0_out[node*KDIM + lane] = a0;
  float t0 = theta0[(0*ZDIM + z)*KDIM + lane];
  float t1 = theta0[(1*ZDIM + z)*KDIM + lane];
  float t2 = theta0[(2*ZDIM + z)*KDIM + lane];
  float q = t0 + t1*a0 + t2*a0*a0;
  __syncthreads();
  lds[w][lane] = q*a0;
  __syncthreads();
  float f = 0.f;
  #pragma unroll 4
  for (int k = 0; k < KDIM; k++) f += lds[w][k] * Wmix0[k*KDIM + lane];
  f += Msc0[z*KDIM + lane];
  float p = f * w_read0[lane];
  p = waveReduce(p);
  if (lane == 0) e_node[node] += p;
  __syncthreads();
  lds[w][lane] = f;
  __syncthreads();
  float h = 0.f, s = 0.f;
  #pragma unroll 2
  for (int k = 0; k < KDIM; k++){
    float fv = lds[w][k];
    h += fv * Wup1[k*KDIM + lane];
    s += fv * Wsc1[(z*KDIM + k)*KDIM + lane];
  }
  h1[node*KDIM + lane] = h;
  sc1[node*KDIM + lane] = s;
}

// ---------------- layer-1 forward + node-local backward (P1/Q shortcut) ----------------
__global__ __launch_bounds__(256) void k_layer1_fwd_bwd(
    const int* z_buf, const int* ptr_r, const int4* pr_pack,
    const float2* Ft2, const float* h1,
    const float* Wout1, const float* theta1, const float* Wmix1,
    const float* sc1, const float* Wr1, const float* Wr2,
    const float* P1, const float* Qtab, const float* WoT1, const float* w_read0,
    float2* gAr2, float* gF1, float* e_node){
  __shared__ float lds[4][KDIM];
  int tid = threadIdx.x;
  int w = tid >> 6, lane = tid & 63;
  int node = blockIdx.x*4 + w;
  int beg = ptr_r[node], end = ptr_r[node+1];
  int deg = end - beg;
  float acc0 = 0.f, acc1 = 0.f, acc2 = 0.f, acc3 = 0.f;
  for (int base = 0; base < deg; base += 64){
    int m = min(64, deg - base);
    float r_l = -1.f; int snd_l = 0;
    if (lane < m){
      int4 pk = pr_pack[beg + base + lane];
      r_l = __int_as_float(pk.x);
      snd_l = pk.y;
    }
    int i = 0;
    GATHER8(snd_l, h1)
  }
  float acc = ((acc0 + acc1) + (acc2 + acc3)) * (1.0f/AVG_NEI_F);
  int z = z_buf[node];
  lds[w][lane] = acc;
  __syncthreads();
  float a0 = 0.f;
  #pragma unroll 4
  for (int k = 0; k < KDIM; k++) a0 += lds[w][k] * Wout1[k*KDIM + lane];
  float t0 = theta1[(0*ZDIM + z)*KDIM + lane];
  float t1 = theta1[(1*ZDIM + z)*KDIM + lane];
  float t2 = theta1[(2*ZDIM + z)*KDIM + lane];
  float q = t0 + t1*a0 + t2*a0*a0;
  __syncthreads();
  lds[w][lane] = q*a0;
  __syncthreads();
  float f = 0.f;
  #pragma unroll 4
  for (int k = 0; k < KDIM; k++) f += lds[w][k] * Wmix1[k*KDIM + lane];
  f += sc1[node*KDIM + lane];
  __syncthreads();
  lds[w][lane] = f;
  __syncthreads();
  // readout: t = feats2 @ Wr1 (16 hidden)
  int hh = lane & 15;
  int quad = lane >> 4;
  float tpart = 0.f;
  #pragma unroll
  for (int jj = 0; jj < 16; jj++)
    tpart += lds[w][quad*16 + jj] * Wr1[(quad*16 + jj)*HIDR + hh];
  tpart += __shfl_xor(tpart, 16);
  tpart += __shfl_xor(tpart, 32);
  float ne = siluf(tpart) * Wr2[hh];
  ne = waveReduce(ne);
  if (lane == 0) e_node[node] += 0.25f * ne;   // private address: no contention
  // ---- backward (node-local), low-rank shortcut through readout ----
  float coeff = dsiluf(tpart) * Wr2[hh];   // replicated x4 across wave
  float gP = 0.f, gsc = 0.f;
  const float* Qz = Qtab + z*HIDR*KDIM;
  #pragma unroll
  for (int h2 = 0; h2 < HIDR; h2++){
    float cc = __shfl(coeff, h2);
    gP  += cc * P1[h2*KDIM + lane];
    gsc += cc * Qz[h2*KDIM + lane];
  }
  gF1[node*KDIM + lane] = w_read0[lane] + gsc;
  float u = t0 + 2.f*t1*a0 + 3.f*t2*a0*a0;
  __syncthreads();
  lds[w][lane] = gP * u;
  __syncthreads();
  float gAr = 0.f;
  #pragma unroll 4
  for (int j = 0; j < KDIM; j++) gAr += lds[w][j] * WoT1[j*KDIM + lane];
  gAr2[node*KDIM + lane].x = gAr * (1.0f/AVG_NEI_F);
}

// LDS pre-reduced energy: 40 blocks x 16 atomics = 640 atomics total
__global__ __launch_bounds__(256) void k_energy(const float* e_node, const int* batch, float* out_e){
  __shared__ float part[G_SEG];
  int tid = threadIdx.x;
  if (tid < G_SEG) part[tid] = 0.f;
  __syncthreads();
  int n = blockIdx.x*256 + tid;
  if (n < N_NODES) atomicAdd(&part[batch[n]], e_node[n]);
  __syncthreads();
  if (tid < G_SEG) atomicAdd(&out_e[tid], part[tid]);
}

// helper for gH0: gather over gAr2c.x (stride-2 float source)
// ---------------- bwd: sender-gather gH + layer-0 node bwd -> gAr0 ----------------
__global__ __launch_bounds__(256) void k_bwd_gH0(
    const int* z_buf, const int* ptr_s, const int4* ps_pack,
    const float2* Ft2, const float2* gAr2c, const float* WupT1, const float* gF1,
    const float* A00, const float* WmixT0, const float* WoT0, const float* theta0,
    float2* gAr2){
  __shared__ float ga[4][KDIM];
  __shared__ float gb[4][KDIM];
  int tid = threadIdx.x; int w = tid>>6, lane = tid&63;
  int node = blockIdx.x*4 + w;
  int beg = ptr_s[node], end = ptr_s[node+1];
  int deg = end - beg;
  float acc0 = 0.f, acc1 = 0.f, acc2 = 0.f, acc3 = 0.f;
  for (int base = 0; base < deg; base += 64){
    int m = min(64, deg - base);
    float r_l = -1.f; int rcv_l = 0;
    if (lane < m){
      int4 pk = ps_pack[beg + base + lane];   // {r, rcv, eid}
      r_l = __int_as_float(pk.x);
      rcv_l = pk.y;
    }
    int i = 0;
    for (; i + 8 <= m; i += 8){
      float r0_ = __shfl(r_l, i),   r1_ = __shfl(r_l, i+1);
      float r2_ = __shfl(r_l, i+2), r3_ = __shfl(r_l, i+3);
      float r4_ = __shfl(r_l, i+4), r5_ = __shfl(r_l, i+5);
      float r6_ = __shfl(r_l, i+6), r7_ = __shfl(r_l, i+7);
      int s0 = __shfl(rcv_l, i),   s1 = __shfl(rcv_l, i+1);
      int s2 = __shfl(rcv_l, i+2), s3 = __shfl(rcv_l, i+3);
      int s4 = __shfl(rcv_l, i+4), s5 = __shfl(rcv_l, i+5);
      int s6 = __shfl(rcv_l, i+6), s7 = __shfl(rcv_l, i+7);
      int b0,b1,b2,b3,b4,b5,b6,b7; float f0,f1,f2,f3,f4,f5,f6,f7, w0,w1,w2,w3,w4,w5,w6,w7;
      r_decode(r0_,b0,f0,w0); r_decode(r1_,b1,f1,w1); r_decode(r2_,b2,f2,w2); r_decode(r3_,b3,f3,w3);
      r_decode(r4_,b4,f4,w4); r_decode(r5_,b5,f5,w5); r_decode(r6_,b6,f6,w6); r_decode(r7_,b7,f7,w7);
      float2 F0 = Ft2[b0*KDIM + lane]; float g0_ = gAr2c[s0*KDIM + lane].x;
      float2 F1 = Ft2[b1*KDIM + lane]; float g1_ = gAr2c[s1*KDIM + lane].x;
      float2 F2 = Ft2[b2*KDIM + lane]; float g2_ = gAr2c[s2*KDIM + lane].x;
      float2 F3 = Ft2[b3*KDIM + lane]; float g3_ = gAr2c[s3*KDIM + lane].x;
      float2 F4 = Ft2[b4*KDIM + lane]; float g4_ = gAr2c[s4*KDIM + lane].x;
      float2 F5 = Ft2[b5*KDIM + lane]; float g5_ = gAr2c[s5*KDIM + lane].x;
      float2 F6 = Ft2[b6*KDIM + lane]; float g6_ = gAr2c[s6*KDIM + lane].x;
      float2 F7 = Ft2[b7*KDIM + lane]; float g7_ = gAr2c[s7*KDIM + lane].x;
      acc0 += w0*(F0.x + f0*(F0.y-F0.x))*g0_; acc1 += w1*(F1.x + f1*(F1.y-F1.x))*g1_;
      acc2 += w2*(F2.x + f2*(F2.y-F2.x))*g2_; acc3 += w3*(F3.x + f3*(F3.y-F3.x))*g3_;
      acc0 += w4*(F4.x + f4*(F4.y-F4.x))*g4_; acc1 += w5*(F5.x + f5*(F5.y-F5.x))*g5_;
      acc2 += w6*(F6.x + f6*(F6.y-F6.x))*g6_; acc3 += w7*(F7.x + f7*(F7.y-F7.x))*g7_;
    }
    for (; i < m; i++){
      float r0_ = __shfl(r_l, i);
      int s0 = __shfl(rcv_l, i);
      int b0; float f0, w0;
      r_decode(r0_, b0, f0, w0);
      float2 F0 = Ft2[b0*KDIM + lane]; float g0_ = gAr2c[s0*KDIM + lane].x;
      acc0 += w0*(F0.x + f0*(F0.y-F0.x))*g0_;
    }
  }
  ga[w][lane] = ((acc0 + acc1) + (acc2 + acc3));
  __syncthreads();
  float gfh = 0.f;
  #pragma unroll 4
  for (int j = 0; j < KDIM; j++) gfh += ga[w][j] * WupT1[j*KDIM + lane];
  float gtot = gF1[node*KDIM + lane] + gfh;
  gb[w][lane] = gtot;
  __syncthreads();
  float gP = 0.f;
  #pragma unroll 4
  for (int j = 0; j < KDIM; j++) gP += gb[w][j] * WmixT0[j*KDIM + lane];
  int z = z_buf[node];
  float a = A00[node*KDIM + lane];
  float t0 = theta0[(0*ZDIM+z)*KDIM + lane];
  float t1 = theta0[(1*ZDIM+z)*KDIM + lane];
  float t2 = theta0[(2*ZDIM+z)*KDIM + lane];
  float u = t0 + 2.f*t1*a + 3.f*t2*a*a;
  __syncthreads();
  ga[w][lane] = gP * u;
  __syncthreads();
  float gAr = 0.f;
  #pragma unroll 4
  for (int j = 0; j < KDIM; j++) gAr += ga[w][j] * WoT0[j*KDIM + lane];
  gAr2[node*KDIM + lane].y = gAr * (1.0f/AVG_NEI_F);
}

// per-edge gr/r -> evec[e].w  (one wave per edge; NO atomics)
__global__ __launch_bounds__(256) void k_gr(const int4* emeta, const float4* dF4,
                                            const float2* gAr2, const float* h1, const float* M0,
                                            float4* evec){
  int tid = threadIdx.x;
  int w = tid>>6, lane = tid&63;
  int e = blockIdx.x*4 + w;
  int4 m = emeta[e];              // {r, snd, rcv, ez}
  float r = __int_as_float(m.x);
  if (r >= RMAXF) return;
  float tp = r * (TBINS / RMAXF);
  int b = (int)tp; if (b > TBINS-1) b = TBINS-1;
  float fr = tp - (float)b;
  float4 d4 = dF4[b*KDIM + lane];           // {d0.lo, d0.hi, d1.lo, d1.hi}
  float2 g  = gAr2[m.z*KDIM + lane];        // {g1, g0}
  float hv1 = h1[m.y*KDIM + lane];
  float hv0 = M0[m.w*KDIM + lane];
  float v = g.x*hv1*(d4.z + fr*(d4.w - d4.z)) + g.y*hv0*(d4.x + fr*(d4.y - d4.x));
  v = waveReduce(v);
  if (lane == 0) evec[e].w = v / r;
}

// force gather: 16 lanes/node, both CSR lists, no atomics
__global__ __launch_bounds__(256) void k_force(const int* ptr_r, const int4* pr_pack,
                                               const int* ptr_s, const int4* ps_pack,
                                               const float4* evec,
                                               float* out_f){
  int tid = threadIdx.x;
  int node = blockIdx.x*16 + (tid >> 4);
  int li = tid & 15;
  float fx=0.f, fy=0.f, fz=0.f;
  int beg = ptr_r[node], end = ptr_r[node+1];
  for (int idx = beg + li; idx < end; idx += 16){
    int e = pr_pack[idx].w;
    float4 ev = evec[e];
    fx -= ev.w*ev.x; fy -= ev.w*ev.y; fz -= ev.w*ev.z;
  }
  beg = ptr_s[node]; end = ptr_s[node+1];
  for (int idx = beg + li; idx < end; idx += 16){
    int e = ps_pack[idx].z;
    float4 ev = evec[e];
    fx += ev.w*ev.x; fy += ev.w*ev.y; fz += ev.w*ev.z;
  }
  #pragma unroll
  for (int off = 8; off > 0; off >>= 1){
    fx += __shfl_xor(fx, off);
    fy += __shfl_xor(fy, off);
    fz += __shfl_xor(fz, off);
  }
  if (li == 0){
    out_f[node*3+0] = fx; out_f[node*3+1] = fy; out_f[node*3+2] = fz;
  }
}

extern "C" void kernel_launch(void* const* d_in, const int* in_sizes, int n_in,
                              void* d_out, int out_size, void* d_ws, size_t ws_size,
                              hipStream_t stream){
  const float* pos    = (const float*)d_in[0];
  const float* attrs  = (const float*)d_in[1];
  const float* shifts = (const float*)d_in[2];
  const float* aE     = (const float*)d_in[3];
  const float* We     = (const float*)d_in[4];
  const float* Wup    = (const float*)d_in[5];
  const float* R1     = (const float*)d_in[6];
  const float* R2     = (const float*)d_in[7];
  const float* R3     = (const float*)d_in[8];
  const float* R4     = (const float*)d_in[9];
  const float* Wout   = (const float*)d_in[10];
  const float* Wsc    = (const float*)d_in[11];
  const float* theta  = (const float*)d_in[12];
  const float* Wmix   = (const float*)d_in[13];
  const float* w_read0= (const float*)d_in[14];
  const float* Wr1    = (const float*)d_in[15];
  const float* Wr2    = (const float*)d_in[16];
  const int*   ei     = (const int*)d_in[17];
  const int*   batch  = (const int*)d_in[18];

  char* base = (char*)d_ws;
  size_t off = 0;
  auto alloc = [&](size_t bytes)->void*{
    void* p = base + off;
    off = (off + bytes + 255) & ~(size_t)255;
    return p;
  };
  float4* evec   = (float4*)alloc(N_EDGES*sizeof(float4));
  int4*   emeta  = (int4*)alloc(N_EDGES*sizeof(int4));
  int4*   pr_pack= (int4*)alloc(N_EDGES*sizeof(int4));
  int4*   ps_pack= (int4*)alloc(N_EDGES*sizeof(int4));
  float*  e_node = (float*)alloc(N_NODES*sizeof(float));
  float*  h1     = (float*)alloc(N_NODES*KDIM*sizeof(float));
  float*  sc1    = (float*)alloc(N_NODES*KDIM*sizeof(float));
  float*  A00    = (float*)alloc(N_NODES*KDIM*sizeof(float));
  float*  gF1    = (float*)alloc(N_NODES*KDIM*sizeof(float));
  float2* gAr2   = (float2*)alloc(N_NODES*KDIM*sizeof(float2));
  float2* Ft2_0  = (float2*)alloc((TBINS+1)*KDIM*sizeof(float2));
  float2* Ft2_1  = (float2*)alloc((TBINS+1)*KDIM*sizeof(float2));
  float4* dF4    = (float4*)alloc((TBINS+1)*KDIM*sizeof(float4));
  float*  M0     = (float*)alloc(ZDIM*KDIM*sizeof(float));
  float*  Msc0   = (float*)alloc(ZDIM*KDIM*sizeof(float));
  float*  WoT0   = (float*)alloc(KDIM*KDIM*sizeof(float));
  float*  WoT1   = (float*)alloc(KDIM*KDIM*sizeof(float));
  float*  WmixT0 = (float*)alloc(KDIM*KDIM*sizeof(float));
  float*  WupT1  = (float*)alloc(KDIM*KDIM*sizeof(float));
  float*  P1     = (float*)alloc(HIDR*KDIM*sizeof(float));
  float*  Qtab   = (float*)alloc(ZDIM*HIDR*KDIM*sizeof(float));
  int* z_buf = (int*)alloc(N_NODES*sizeof(int));
  int* cnt_r = (int*)alloc(N_NODES*sizeof(int));
  int* cnt_s = (int*)alloc(N_NODES*sizeof(int));
  int* ptr_r = (int*)alloc((N_NODES+1)*sizeof(int));
  int* ptr_s = (int*)alloc((N_NODES+1)*sizeof(int));
  int* cur_r = (int*)alloc(N_NODES*sizeof(int));
  int* cur_s = (int*)alloc(N_NODES*sizeof(int));

  float* out_e = (float*)d_out;
  float* out_f = out_e + G_SEG;

  hipMemsetAsync(d_out, 0, (size_t)out_size*sizeof(float), stream);
  hipMemsetAsync(cnt_r, 0, N_NODES*sizeof(int), stream);
  hipMemsetAsync(cnt_s, 0, N_NODES*sizeof(int), stream);

  const int NB4 = N_NODES/4;
  const int EB  = N_EDGES/256;
  const int EB4 = N_EDGES/4;
  const int NBt = (N_NODES+255)/256;

  const float* Wup1 = Wup + KDIM*KDIM;
  const float* Wsc1 = Wsc + ZDIM*KDIM*KDIM;
  const float* Wout1 = Wout + 3*KDIM*KDIM;
  const float* theta1 = theta + 3*ZDIM*KDIM;
  const float* Wmix1 = Wmix + KDIM*KDIM;

  k_setup<<<153,256,0,stream>>>(We, Wup, Wsc, Wout, Wmix, Wr1, attrs, aE,
                                M0, Msc0, WoT0, WoT1, WmixT0, WupT1, P1, Qtab,
                                z_buf, e_node);
  k_table<<<TBINS+1,64,0,stream>>>(R1, R2, R3, R4, Ft2_0, Ft2_1, (float*)dF4);
  k_edge_setup<<<EB,256,0,stream>>>(pos, shifts, ei, z_buf, evec, emeta, cnt_r, cnt_s);
  k_scan<<<2,1024,0,stream>>>(cnt_r, ptr_r, cur_r, cnt_s, ptr_s, cur_s);
  k_fill<<<EB,256,0,stream>>>(emeta, cur_r, cur_s, pr_pack, ps_pack);

  // ---- forward ----
  k_layer0_fwd<<<NB4,256,0,stream>>>(z_buf, ptr_r, pr_pack, Ft2_0, M0,
      Wout, theta, Wmix, Msc0, w_read0, Wup1, Wsc1,
      A00, h1, sc1, e_node);
  k_layer1_fwd_bwd<<<NB4,256,0,stream>>>(z_buf, ptr_r, pr_pack, Ft2_1, h1,
      Wout1, theta1, Wmix1, sc1, Wr1, Wr2,
      P1, Qtab, WoT1, w_read0,
      gAr2, gF1, e_node);
  k_energy<<<NBt,256,0,stream>>>(e_node, batch, out_e);

  // ---- backward ----
  k_bwd_gH0<<<NB4,256,0,stream>>>(z_buf, ptr_s, ps_pack, Ft2_1, gAr2, WupT1, gF1,
      A00, WmixT0, WoT0, theta, gAr2);
  k_gr<<<EB4,256,0,stream>>>(emeta, dF4, gAr2, h1, M0, evec);
  k_force<<<N_NODES/16,256,0,stream>>>(ptr_r, pr_pack, ptr_s, ps_pack, evec, out_f);
}

// Round 10
// 299.878 us; speedup vs baseline: 1.0485x; 1.0485x over previous
//
#include <hip/hip_runtime.h>
#include <math.h>

#define N_NODES 10000
#define N_EDGES 160000
#define G_SEG 16
#define ZDIM 10
#define KDIM 64
#define NBESS 8
#define HIDR 16
#define RMAXF 5.0f
#define AVG_NEI_F 16.0f
#define TBINS 256

__device__ __forceinline__ float siluf(float x){ float s = 1.0f/(1.0f+expf(-x)); return x*s; }
__device__ __forceinline__ float dsiluf(float x){ float s = 1.0f/(1.0f+expf(-x)); return s*(1.0f + x*(1.0f-s)); }

__device__ __forceinline__ float waveReduce(float v){
  for (int off = 32; off > 0; off >>= 1) v += __shfl_down(v, off);
  return v;
}

// decode from r (CSR slots hold r; padding holds -1 -> wm=0, b=0)
__device__ __forceinline__ void r_decode(float r, int& b, float& fr, float& wm){
  wm = (r >= 0.f) ? 1.f : 0.f;
  float tp = fmaxf(r, 0.f) * (TBINS / RMAXF);
  b = (int)tp; if (b > TBINS-1) b = TBINS-1;
  fr = tp - (float)b;
}

// K=64 matvec with 4 independent accumulator chains (fp adds can't be
// reassociated by the compiler; serial chain was 64 dependent FMAs)
#define MATVEC64(SRCROW, W, OUTV) \
  { float m0_=0.f,m1_=0.f,m2_=0.f,m3_=0.f; \
    for (int k_ = 0; k_ < KDIM; k_ += 4){ \
      m0_ += SRCROW[k_]   * W[(k_)*KDIM + lane]; \
      m1_ += SRCROW[k_+1] * W[(k_+1)*KDIM + lane]; \
      m2_ += SRCROW[k_+2] * W[(k_+2)*KDIM + lane]; \
      m3_ += SRCROW[k_+3] * W[(k_+3)*KDIM + lane]; \
    } OUTV = (m0_+m1_)+(m2_+m3_); }

// ---------------- merged setup ----------------
__global__ __launch_bounds__(256) void k_setup(
    const float* We, const float* Wup, const float* Wsc,
    const float* Wout, const float* Wmix,
    const float* Wr1,
    const float* attrs, const float* aE,
    float* M0, float* Msc0,
    float* WoT0, float* WoT1, float* WmixT0, float* WupT1,
    float* P1, float* Qtab,
    int* z_buf, float* e_node){
  int blk = blockIdx.x, tid = threadIdx.x;
  const float* Wmix1 = Wmix + KDIM*KDIM;
  const float* Wsc1  = Wsc + ZDIM*KDIM*KDIM;
  if (blk < 5){
    int idx = blk*256 + tid;
    if (idx < 1280){
      int which = idx >= 640;
      int t = which ? idx - 640 : idx;
      int z = t >> 6, j = t & 63;
      float acc = 0.f;
      if (!which){
        #pragma unroll 8
        for (int k = 0; k < KDIM; k++) acc += We[z*KDIM + k] * Wup[k*KDIM + j];
        M0[z*KDIM + j] = acc;
      } else {
        #pragma unroll 8
        for (int k = 0; k < KDIM; k++) acc += We[z*KDIM + k] * Wsc[(z*KDIM + k)*KDIM + j];
        Msc0[z*KDIM + j] = acc;
      }
    }
  } else if (blk < 69){
    int t = (blk-5)*256 + tid;   // 0..16383
    int arr = t >> 12;
    int rem = t & 4095;
    int j = rem >> 6, k = rem & 63;
    float v; float* dst;
    switch(arr){
      case 0: v = Wout[k*KDIM + j];                 dst = WoT0;   break;
      case 1: v = Wout[3*KDIM*KDIM + k*KDIM + j];   dst = WoT1;   break;
      case 2: v = Wmix[k*KDIM + j];                 dst = WmixT0; break;
      default:v = Wup[KDIM*KDIM + k*KDIM + j];      dst = WupT1;  break;
    }
    dst[rem] = v;
  } else if (blk < 73){
    int t = (blk-69)*256 + tid;  // 0..1023
    int h = t >> 6, k = t & 63;
    float acc = 0.f;
    #pragma unroll 8
    for (int j = 0; j < KDIM; j++) acc += Wr1[j*HIDR + h] * Wmix1[k*KDIM + j];
    P1[h*KDIM + k] = acc;
  } else if (blk < 113){
    int t = (blk-73)*256 + tid;  // 0..10239
    int z = t >> 10;
    int rem = t & 1023;
    int h = rem >> 6, k = rem & 63;
    float acc = 0.f;
    #pragma unroll 8
    for (int j = 0; j < KDIM; j++) acc += Wr1[j*HIDR + h] * Wsc1[(z*KDIM + k)*KDIM + j];
    Qtab[(z*HIDR + h)*KDIM + k] = acc;
  } else {
    int n = (blk-113)*256 + tid;
    if (n < N_NODES){
      int z = 0;
      for (int i = 1; i < ZDIM; i++) if (attrs[n*ZDIM+i] > 0.5f) z = i;
      z_buf[n] = z;
      e_node[n] = aE[z];
    }
  }
}

// edge geometry + packed edge meta + CSR degree counting (live edges only)
__global__ __launch_bounds__(256) void k_edge_setup(const float* pos, const float* shifts, const int* ei,
                                                    const int* z_buf,
                                                    float4* evec, int4* emeta,
                                                    int* cnt_r, int* cnt_s){
  int e = blockIdx.x*256 + threadIdx.x;
  int s = ei[e], rcv = ei[N_EDGES + e];
  float dx = pos[rcv*3+0] - pos[s*3+0] + shifts[e*3+0];
  float dy = pos[rcv*3+1] - pos[s*3+1] + shifts[e*3+1];
  float dz = pos[rcv*3+2] - pos[s*3+2] + shifts[e*3+2];
  float r = sqrtf(dx*dx + dy*dy + dz*dz + 1e-9f);
  evec[e] = make_float4(dx, dy, dz, r);
  emeta[e] = make_int4(__float_as_int(r), s, rcv, z_buf[s]);
  if (r < RMAXF){
    atomicAdd(&cnt_s[s], 1);
    atomicAdd(&cnt_r[rcv], 1);
  }
}

__global__ __launch_bounds__(1024) void k_scan(const int* cnt_r, int* ptr_r, int* cur_r,
                                               const int* cnt_s, int* ptr_s, int* cur_s){
  __shared__ int part[1024];
  int tid = threadIdx.x;
  const int* cnt = blockIdx.x ? cnt_s : cnt_r;
  int* ptr = blockIdx.x ? ptr_s : ptr_r;
  int* cur = blockIdx.x ? cur_s : cur_r;
  const int per = 10;
  int start = tid*per;
  int s = 0;
  for (int t = 0; t < per; t++){ int i = start + t; if (i < N_NODES) s += cnt[i]; }
  part[tid] = s; __syncthreads();
  for (int d = 1; d < 1024; d <<= 1){
    int v = (tid >= d) ? part[tid-d] : 0;
    __syncthreads();
    part[tid] += v;
    __syncthreads();
  }
  int run = part[tid] - s;
  for (int t = 0; t < per; t++){
    int i = start + t;
    if (i < N_NODES){ ptr[i] = run; cur[i] = run; run += cnt[i]; }
  }
  if (tid == 1023) ptr[N_NODES] = part[1023];
}

__global__ __launch_bounds__(256) void k_fill(const int4* emeta, int* cur_r, int* cur_s,
                                              int4* pr_pack, int4* ps_pack){
  int e = blockIdx.x*256 + threadIdx.x;
  int4 m = emeta[e];            // {r_bits, snd, rcv, ez}
  float r = __int_as_float(m.x);
  if (r >= RMAXF) return;
  int p = atomicAdd(&cur_s[m.y], 1);
  ps_pack[p] = make_int4(m.x, m.z, e, 0);          // {r, rcv, eid}
  int p2 = atomicAdd(&cur_r[m.z], 1);
  pr_pack[p2] = make_int4(m.x, m.y, m.w, e);       // {r, snd, ez, eid}
}

// ---------------- radial-MLP tables ----------------
__global__ __launch_bounds__(64) void k_table(const float* R1g, const float* R2g,
                                              const float* R3g, const float* R4g,
                                              float2* Ft2_0, float2* Ft2_1, float* dF4f){
  int t = blockIdx.x, j = threadIdx.x;
  __shared__ float efs[NBESS], defs[NBESS];
  __shared__ float xs[KDIM], dxs[KDIM];
  if (j < NBESS){
    double r = (double)t * (double)RMAXF / (double)TBINS;
    double w = (double)(j+1) * M_PI / (double)RMAXF;
    double c = sqrt(2.0 / (double)RMAXF);
    double bess, dbess;
    if (r < 1e-12){ bess = c*w; dbess = 0.0; }
    else {
      double sw = sin(w*r), cw = cos(w*r);
      bess = c*sw/r;
      dbess = c*(w*cw*r - sw)/(r*r);
    }
    double xx = r / (double)RMAXF;
    double f = 0.0, df = 0.0;
    if (xx < 1.0){
      double x2 = xx*xx, x4 = x2*x2, x5 = x4*xx, x6 = x5*xx, x7 = x6*xx;
      f = 1.0 - 21.0*x5 + 35.0*x6 - 15.0*x7;
      df = (-105.0*x4 + 210.0*x5 - 105.0*x6) / (double)RMAXF;
    }
    efs[j]  = (float)(bess*f);
    defs[j] = (float)(dbess*f + bess*df);
  }
  __syncthreads();
  for (int i = 0; i < 2; i++){
    const float* R1 = R1g + i*NBESS*KDIM;
    const float* R2 = R2g + i*KDIM*KDIM;
    const float* R3 = R3g + i*KDIM*KDIM;
    const float* R4 = R4g + i*KDIM*KDIM;
    float z = 0.f, dz = 0.f;
    for (int b = 0; b < NBESS; b++){ float w = R1[b*KDIM+j]; z += efs[b]*w; dz += defs[b]*w; }
    float v = siluf(z), dv = dsiluf(z)*dz;
    xs[j] = v; dxs[j] = dv; __syncthreads();
    z = 0.f; dz = 0.f;
    for (int k = 0; k < KDIM; k++){ float w = R2[k*KDIM+j]; z += xs[k]*w; dz += dxs[k]*w; }
    v = siluf(z); dv = dsiluf(z)*dz; __syncthreads();
    xs[j] = v; dxs[j] = dv; __syncthreads();
    z = 0.f; dz = 0.f;
    for (int k = 0; k < KDIM; k++){ float w = R3[k*KDIM+j]; z += xs[k]*w; dz += dxs[k]*w; }
    v = siluf(z); dv = dsiluf(z)*dz; __syncthreads();
    xs[j] = v; dxs[j] = dv; __syncthreads();
    z = 0.f; dz = 0.f;
    for (int k = 0; k < KDIM; k++){ float w = R4[k*KDIM+j]; z += xs[k]*w; dz += dxs[k]*w; }
    float2* Ft  = i ? Ft2_1 : Ft2_0;
    Ft[t*KDIM+j].x = z;  if (t > 0) Ft[(t-1)*KDIM+j].y = z;
    dF4f[(t*KDIM+j)*4 + 2*i] = dz;
    if (t > 0) dF4f[((t-1)*KDIM+j)*4 + 2*i + 1] = dz;
    __syncthreads();
  }
}

// 8-edge-deep tail-free gather: m rounded up to 8; lanes >= m carry r=-1 (wm=0).
#define GATHER8(IDXSRC, ROWPTR) \
    { int mr = (m + 7) & ~7; \
    for (int i = 0; i < mr; i += 8){ \
      float r0_ = __shfl(r_l, i),   r1_ = __shfl(r_l, i+1); \
      float r2_ = __shfl(r_l, i+2), r3_ = __shfl(r_l, i+3); \
      float r4_ = __shfl(r_l, i+4), r5_ = __shfl(r_l, i+5); \
      float r6_ = __shfl(r_l, i+6), r7_ = __shfl(r_l, i+7); \
      int s0 = __shfl(IDXSRC, i),   s1 = __shfl(IDXSRC, i+1); \
      int s2 = __shfl(IDXSRC, i+2), s3 = __shfl(IDXSRC, i+3); \
      int s4 = __shfl(IDXSRC, i+4), s5 = __shfl(IDXSRC, i+5); \
      int s6 = __shfl(IDXSRC, i+6), s7 = __shfl(IDXSRC, i+7); \
      int b0,b1,b2,b3,b4,b5,b6,b7; float f0,f1,f2,f3,f4,f5,f6,f7, w0,w1,w2,w3,w4,w5,w6,w7; \
      r_decode(r0_,b0,f0,w0); r_decode(r1_,b1,f1,w1); r_decode(r2_,b2,f2,w2); r_decode(r3_,b3,f3,w3); \
      r_decode(r4_,b4,f4,w4); r_decode(r5_,b5,f5,w5); r_decode(r6_,b6,f6,w6); r_decode(r7_,b7,f7,w7); \
      float2 F0 = Ft2[b0*KDIM + lane]; float h0_ = ROWPTR[s0*KDIM + lane]; \
      float2 F1 = Ft2[b1*KDIM + lane]; float h1_ = ROWPTR[s1*KDIM + lane]; \
      float2 F2 = Ft2[b2*KDIM + lane]; float h2_ = ROWPTR[s2*KDIM + lane]; \
      float2 F3 = Ft2[b3*KDIM + lane]; float h3_ = ROWPTR[s3*KDIM + lane]; \
      float2 F4 = Ft2[b4*KDIM + lane]; float h4_ = ROWPTR[s4*KDIM + lane]; \
      float2 F5 = Ft2[b5*KDIM + lane]; float h5_ = ROWPTR[s5*KDIM + lane]; \
      float2 F6 = Ft2[b6*KDIM + lane]; float h6_ = ROWPTR[s6*KDIM + lane]; \
      float2 F7 = Ft2[b7*KDIM + lane]; float h7_ = ROWPTR[s7*KDIM + lane]; \
      acc0 += w0*(F0.x + f0*(F0.y-F0.x))*h0_; acc1 += w1*(F1.x + f1*(F1.y-F1.x))*h1_; \
      acc2 += w2*(F2.x + f2*(F2.y-F2.x))*h2_; acc3 += w3*(F3.x + f3*(F3.y-F3.x))*h3_; \
      acc0 += w4*(F4.x + f4*(F4.y-F4.x))*h4_; acc1 += w5*(F5.x + f5*(F5.y-F5.x))*h5_; \
      acc2 += w6*(F6.x + f6*(F6.y-F6.x))*h6_; acc3 += w7*(F7.x + f7*(F7.y-F7.x))*h7_; \
    } }

// ---------------- layer-0 forward (M0-table gather) + epilogue + h1/sc1 ----------------
__global__ __launch_bounds__(256) void k_layer0_fwd(
    const int* z_buf, const int* ptr_r, const int4* pr_pack,
    const float2* Ft2, const float* M0,
    const float* Wout0, const float* theta0, const float* Wmix0,
    const float* Msc0, const float* w_read0,
    const float* Wup1, const float* Wsc1,
    float* A0_out, float* h1, float* sc1, float* e_node){
  __shared__ float lds[4][KDIM];
  int tid = threadIdx.x;
  int w = tid >> 6, lane = tid & 63;
  int node = blockIdx.x*4 + w;
  int z = z_buf[node];
  int beg = ptr_r[node], end = ptr_r[node+1];
  int deg = end - beg;
  float acc0 = 0.f, acc1 = 0.f, acc2 = 0.f, acc3 = 0.f;
  for (int base = 0; base < deg; base += 64){
    int m = min(64, deg - base);
    float r_l = -1.f; int sz_l = 0;
    if (lane < m){
      int4 pk = pr_pack[beg + base + lane];   // {r, snd, ez, eid}
      r_l = __int_as_float(pk.x);
      sz_l = pk.z;
    }
    GATHER8(sz_l, M0)
  }
  float acc = ((acc0 + acc1) + (acc2 + acc3)) * (1.0f/AVG_NEI_F);
  lds[w][lane] = acc;
  __syncthreads();
  float a0;
  MATVEC64(lds[w], Wout0, a0)
  A0_out[node*KDIM + lane] = a0;
  float t0 = theta0[(0*ZDIM + z)*KDIM + lane];
  float t1 = theta0[(1*ZDIM + z)*KDIM + lane];
  float t2 = theta0[(2*ZDIM + z)*KDIM + lane];
  float q = t0 + t1*a0 + t2*a0*a0;
  __syncthreads();
  lds[w][lane] = q*a0;
  __syncthreads();
  float f;
  MATVEC64(lds[w], Wmix0, f)
  f += Msc0[z*KDIM + lane];
  float p = f * w_read0[lane];
  p = waveReduce(p);
  if (lane == 0) e_node[node] += p;
  __syncthreads();
  lds[w][lane] = f;
  __syncthreads();
  // fused h1/sc1: 2 chains each
  {
    float h0_=0.f,h1_=0.f,s0_=0.f,s1_=0.f;
    const float* Wz = Wsc1 + z*KDIM*KDIM;
    for (int k = 0; k < KDIM; k += 2){
      float f0_ = lds[w][k], f1_ = lds[w][k+1];
      h0_ += f0_ * Wup1[k*KDIM + lane];
      h1_ += f1_ * Wup1[(k+1)*KDIM + lane];
      s0_ += f0_ * Wz[k*KDIM + lane];
      s1_ += f1_ * Wz[(k+1)*KDIM + lane];
    }
    h1[node*KDIM + lane] = h0_ + h1_;
    sc1[node*KDIM + lane] = s0_ + s1_;
  }
}

// ---------------- layer-1 forward + node-local backward (P1/Q shortcut) ----------------
__global__ __launch_bounds__(256) void k_layer1_fwd_bwd(
    const int* z_buf, const int* ptr_r, const int4* pr_pack,
    const float2* Ft2, const float* h1,
    const float* Wout1, const float* theta1, const float* Wmix1,
    const float* sc1, const float* Wr1, const float* Wr2,
    const float* P1, const float* Qtab, const float* WoT1, const float* w_read0,
    float2* gAr2, float* gF1, float* e_node){
  __shared__ float lds[4][KDIM];
  int tid = threadIdx.x;
  int w = tid >> 6, lane = tid & 63;
  int node = blockIdx.x*4 + w;
  int beg = ptr_r[node], end = ptr_r[node+1];
  int deg = end - beg;
  float acc0 = 0.f, acc1 = 0.f, acc2 = 0.f, acc3 = 0.f;
  for (int base = 0; base < deg; base += 64){
    int m = min(64, deg - base);
    float r_l = -1.f; int snd_l = 0;
    if (lane < m){
      int4 pk = pr_pack[beg + base + lane];
      r_l = __int_as_float(pk.x);
      snd_l = pk.y;
    }
    GATHER8(snd_l, h1)
  }
  float acc = ((acc0 + acc1) + (acc2 + acc3)) * (1.0f/AVG_NEI_F);
  int z = z_buf[node];
  lds[w][lane] = acc;
  __syncthreads();
  float a0;
  MATVEC64(lds[w], Wout1, a0)
  float t0 = theta1[(0*ZDIM + z)*KDIM + lane];
  float t1 = theta1[(1*ZDIM + z)*KDIM + lane];
  float t2 = theta1[(2*ZDIM + z)*KDIM + lane];
  float q = t0 + t1*a0 + t2*a0*a0;
  __syncthreads();
  lds[w][lane] = q*a0;
  __syncthreads();
  float f;
  MATVEC64(lds[w], Wmix1, f)
  f += sc1[node*KDIM + lane];
  __syncthreads();
  lds[w][lane] = f;
  __syncthreads();
  // readout: t = feats2 @ Wr1 (16 hidden)
  int hh = lane & 15;
  int quad = lane >> 4;
  float tpart = 0.f;
  #pragma unroll
  for (int jj = 0; jj < 16; jj++)
    tpart += lds[w][quad*16 + jj] * Wr1[(quad*16 + jj)*HIDR + hh];
  tpart += __shfl_xor(tpart, 16);
  tpart += __shfl_xor(tpart, 32);
  float ne = siluf(tpart) * Wr2[hh];
  ne = waveReduce(ne);
  if (lane == 0) e_node[node] += 0.25f * ne;   // private address: no contention
  // ---- backward (node-local), low-rank shortcut through readout ----
  float coeff = dsiluf(tpart) * Wr2[hh];   // replicated x4 across wave
  float gP0 = 0.f, gP1 = 0.f, gs0 = 0.f, gs1 = 0.f;
  const float* Qz = Qtab + z*HIDR*KDIM;
  #pragma unroll
  for (int h2 = 0; h2 < HIDR; h2 += 2){
    float c0 = __shfl(coeff, h2);
    float c1 = __shfl(coeff, h2+1);
    gP0 += c0 * P1[h2*KDIM + lane];
    gP1 += c1 * P1[(h2+1)*KDIM + lane];
    gs0 += c0 * Qz[h2*KDIM + lane];
    gs1 += c1 * Qz[(h2+1)*KDIM + lane];
  }
  float gP = gP0 + gP1;
  gF1[node*KDIM + lane] = w_read0[lane] + gs0 + gs1;
  float u = t0 + 2.f*t1*a0 + 3.f*t2*a0*a0;
  __syncthreads();
  lds[w][lane] = gP * u;
  __syncthreads();
  float gAr;
  MATVEC64(lds[w], WoT1, gAr)
  gAr2[node*KDIM + lane].x = gAr * (1.0f/AVG_NEI_F);
}

// LDS pre-reduced energy: 40 blocks x 16 atomics = 640 atomics total
__global__ __launch_bounds__(256) void k_energy(const float* e_node, const int* batch, float* out_e){
  __shared__ float part[G_SEG];
  int tid = threadIdx.x;
  if (tid < G_SEG) part[tid] = 0.f;
  __syncthreads();
  int n = blockIdx.x*256 + tid;
  if (n < N_NODES) atomicAdd(&part[batch[n]], e_node[n]);
  __syncthreads();
  if (tid < G_SEG) atomicAdd(&out_e[tid], part[tid]);
}

// ---------------- bwd: sender-gather gH + layer-0 node bwd -> gAr0 ----------------
__global__ __launch_bounds__(256) void k_bwd_gH0(
    const int* z_buf, const int* ptr_s, const int4* ps_pack,
    const float2* Ft2, const float2* gAr2c, const float* WupT1, const float* gF1,
    const float* A00, const float* WmixT0, const float* WoT0, const float* theta0,
    float2* gAr2){
  __shared__ float ga[4][KDIM];
  __shared__ float gb[4][KDIM];
  int tid = threadIdx.x; int w = tid>>6, lane = tid&63;
  int node = blockIdx.x*4 + w;
  int beg = ptr_s[node], end = ptr_s[node+1];
  int deg = end - beg;
  float acc0 = 0.f, acc1 = 0.f, acc2 = 0.f, acc3 = 0.f;
  for (int base = 0; base < deg; base += 64){
    int m = min(64, deg - base);
    float r_l = -1.f; int rcv_l = 0;
    if (lane < m){
      int4 pk = ps_pack[beg + base + lane];   // {r, rcv, eid}
      r_l = __int_as_float(pk.x);
      rcv_l = pk.y;
    }
    int mr = (m + 7) & ~7;
    for (int i = 0; i < mr; i += 8){
      float r0_ = __shfl(r_l, i),   r1_ = __shfl(r_l, i+1);
      float r2_ = __shfl(r_l, i+2), r3_ = __shfl(r_l, i+3);
      float r4_ = __shfl(r_l, i+4), r5_ = __shfl(r_l, i+5);
      float r6_ = __shfl(r_l, i+6), r7_ = __shfl(r_l, i+7);
      int s0 = __shfl(rcv_l, i),   s1 = __shfl(rcv_l, i+1);
      int s2 = __shfl(rcv_l, i+2), s3 = __shfl(rcv_l, i+3);
      int s4 = __shfl(rcv_l, i+4), s5 = __shfl(rcv_l, i+5);
      int s6 = __shfl(rcv_l, i+6), s7 = __shfl(rcv_l, i+7);
      int b0,b1,b2,b3,b4,b5,b6,b7; float f0,f1,f2,f3,f4,f5,f6,f7, w0,w1,w2,w3,w4,w5,w6,w7;
      r_decode(r0_,b0,f0,w0); r_decode(r1_,b1,f1,w1); r_decode(r2_,b2,f2,w2); r_decode(r3_,b3,f3,w3);
      r_decode(r4_,b4,f4,w4); r_decode(r5_,b5,f5,w5); r_decode(r6_,b6,f6,w6); r_decode(r7_,b7,f7,w7);
      float2 F0 = Ft2[b0*KDIM + lane]; float g0_ = gAr2c[s0*KDIM + lane].x;
      float2 F1 = Ft2[b1*KDIM + lane]; float g1_ = gAr2c[s1*KDIM + lane].x;
      float2 F2 = Ft2[b2*KDIM + lane]; float g2_ = gAr2c[s2*KDIM + lane].x;
      float2 F3 = Ft2[b3*KDIM + lane]; float g3_ = gAr2c[s3*KDIM + lane].x;
      float2 F4 = Ft2[b4*KDIM + lane]; float g4_ = gAr2c[s4*KDIM + lane].x;
      float2 F5 = Ft2[b5*KDIM + lane]; float g5_ = gAr2c[s5*KDIM + lane].x;
      float2 F6 = Ft2[b6*KDIM + lane]; float g6_ = gAr2c[s6*KDIM + lane].x;
      float2 F7 = Ft2[b7*KDIM + lane]; float g7_ = gAr2c[s7*KDIM + lane].x;
      acc0 += w0*(F0.x + f0*(F0.y-F0.x))*g0_; acc1 += w1*(F1.x + f1*(F1.y-F1.x))*g1_;
      acc2 += w2*(F2.x + f2*(F2.y-F2.x))*g2_; acc3 += w3*(F3.x + f3*(F3.y-F3.x))*g3_;
      acc0 += w4*(F4.x + f4*(F4.y-F4.x))*g4_; acc1 += w5*(F5.x + f5*(F5.y-F5.x))*g5_;
      acc2 += w6*(F6.x + f6*(F6.y-F6.x))*g6_; acc3 += w7*(F7.x + f7*(F7.y-F7.x))*g7_;
    }
  }
  ga[w][lane] = ((acc0 + acc1) + (acc2 + acc3));
  __syncthreads();
  float gfh;
  MATVEC64(ga[w], WupT1, gfh)
  float gtot = gF1[node*KDIM + lane] + gfh;
  __syncthreads();
  gb[w][lane] = gtot;
  __syncthreads();
  float gP;
  MATVEC64(gb[w], WmixT0, gP)
  int z = z_buf[node];
  float a = A00[node*KDIM + lane];
  float t0 = theta0[(0*ZDIM+z)*KDIM + lane];
  float t1 = theta0[(1*ZDIM+z)*KDIM + lane];
  float t2 = theta0[(2*ZDIM+z)*KDIM + lane];
  float u = t0 + 2.f*t1*a + 3.f*t2*a*a;
  __syncthreads();
  ga[w][lane] = gP * u;
  __syncthreads();
  float gAr;
  MATVEC64(ga[w], WoT0, gAr)
  gAr2[node*KDIM + lane].y = gAr * (1.0f/AVG_NEI_F);
}

// per-edge gr/r -> evec[e].w  (one wave per edge; NO atomics)
__global__ __launch_bounds__(256) void k_gr(const int4* emeta, const float4* dF4,
                                            const float2* gAr2, const float* h1, const float* M0,
                                            float4* evec){
  int tid = threadIdx.x;
  int w = tid>>6, lane = tid&63;
  int e = blockIdx.x*4 + w;
  int4 m = emeta[e];              // {r, snd, rcv, ez}
  float r = __int_as_float(m.x);
  if (r >= RMAXF) return;
  float tp = r * (TBINS / RMAXF);
  int b = (int)tp; if (b > TBINS-1) b = TBINS-1;
  float fr = tp - (float)b;
  float4 d4 = dF4[b*KDIM + lane];           // {d0.lo, d0.hi, d1.lo, d1.hi}
  float2 g  = gAr2[m.z*KDIM + lane];        // {g1, g0}
  float hv1 = h1[m.y*KDIM + lane];
  float hv0 = M0[m.w*KDIM + lane];
  float v = g.x*hv1*(d4.z + fr*(d4.w - d4.z)) + g.y*hv0*(d4.x + fr*(d4.y - d4.x));
  v = waveReduce(v);
  if (lane == 0) evec[e].w = v / r;
}

// force gather: 16 lanes/node, both CSR lists, no atomics
__global__ __launch_bounds__(256) void k_force(const int* ptr_r, const int4* pr_pack,
                                               const int* ptr_s, const int4* ps_pack,
                                               const float4* evec,
                                               float* out_f){
  int tid = threadIdx.x;
  int node = blockIdx.x*16 + (tid >> 4);
  int li = tid & 15;
  float fx=0.f, fy=0.f, fz=0.f;
  int beg = ptr_r[node], end = ptr_r[node+1];
  for (int idx = beg + li; idx < end; idx += 16){
    int e = pr_pack[idx].w;
    float4 ev = evec[e];
    fx -= ev.w*ev.x; fy -= ev.w*ev.y; fz -= ev.w*ev.z;
  }
  beg = ptr_s[node]; end = ptr_s[node+1];
  for (int idx = beg + li; idx < end; idx += 16){
    int e = ps_pack[idx].z;
    float4 ev = evec[e];
    fx += ev.w*ev.x; fy += ev.w*ev.y; fz += ev.w*ev.z;
  }
  #pragma unroll
  for (int off = 8; off > 0; off >>= 1){
    fx += __shfl_xor(fx, off);
    fy += __shfl_xor(fy, off);
    fz += __shfl_xor(fz, off);
  }
  if (li == 0){
    out_f[node*3+0] = fx; out_f[node*3+1] = fy; out_f[node*3+2] = fz;
  }
}

extern "C" void kernel_launch(void* const* d_in, const int* in_sizes, int n_in,
                              void* d_out, int out_size, void* d_ws, size_t ws_size,
                              hipStream_t stream){
  const float* pos    = (const float*)d_in[0];
  const float* attrs  = (const float*)d_in[1];
  const float* shifts = (const float*)d_in[2];
  const float* aE     = (const float*)d_in[3];
  const float* We     = (const float*)d_in[4];
  const float* Wup    = (const float*)d_in[5];
  const float* R1     = (const float*)d_in[6];
  const float* R2     = (const float*)d_in[7];
  const float* R3     = (const float*)d_in[8];
  const float* R4     = (const float*)d_in[9];
  const float* Wout   = (const float*)d_in[10];
  const float* Wsc    = (const float*)d_in[11];
  const float* theta  = (const float*)d_in[12];
  const float* Wmix   = (const float*)d_in[13];
  const float* w_read0= (const float*)d_in[14];
  const float* Wr1    = (const float*)d_in[15];
  const float* Wr2    = (const float*)d_in[16];
  const int*   ei     = (const int*)d_in[17];
  const int*   batch  = (const int*)d_in[18];

  char* base = (char*)d_ws;
  size_t off = 0;
  auto alloc = [&](size_t bytes)->void*{
    void* p = base + off;
    off = (off + bytes + 255) & ~(size_t)255;
    return p;
  };
  float4* evec   = (float4*)alloc(N_EDGES*sizeof(float4));
  int4*   emeta  = (int4*)alloc(N_EDGES*sizeof(int4));
  int4*   pr_pack= (int4*)alloc(N_EDGES*sizeof(int4));
  int4*   ps_pack= (int4*)alloc(N_EDGES*sizeof(int4));
  float*  e_node = (float*)alloc(N_NODES*sizeof(float));
  float*  h1     = (float*)alloc(N_NODES*KDIM*sizeof(float));
  float*  sc1    = (float*)alloc(N_NODES*KDIM*sizeof(float));
  float*  A00    = (float*)alloc(N_NODES*KDIM*sizeof(float));
  float*  gF1    = (float*)alloc(N_NODES*KDIM*sizeof(float));
  float2* gAr2   = (float2*)alloc(N_NODES*KDIM*sizeof(float2));
  float2* Ft2_0  = (float2*)alloc((TBINS+1)*KDIM*sizeof(float2));
  float2* Ft2_1  = (float2*)alloc((TBINS+1)*KDIM*sizeof(float2));
  float4* dF4    = (float4*)alloc((TBINS+1)*KDIM*sizeof(float4));
  float*  M0     = (float*)alloc(ZDIM*KDIM*sizeof(float));
  float*  Msc0   = (float*)alloc(ZDIM*KDIM*sizeof(float));
  float*  WoT0   = (float*)alloc(KDIM*KDIM*sizeof(float));
  float*  WoT1   = (float*)alloc(KDIM*KDIM*sizeof(float));
  float*  WmixT0 = (float*)alloc(KDIM*KDIM*sizeof(float));
  float*  WupT1  = (float*)alloc(KDIM*KDIM*sizeof(float));
  float*  P1     = (float*)alloc(HIDR*KDIM*sizeof(float));
  float*  Qtab   = (float*)alloc(ZDIM*HIDR*KDIM*sizeof(float));
  int* z_buf = (int*)alloc(N_NODES*sizeof(int));
  int* cnt_r = (int*)alloc(N_NODES*sizeof(int));
  int* cnt_s = (int*)alloc(N_NODES*sizeof(int));
  int* ptr_r = (int*)alloc((N_NODES+1)*sizeof(int));
  int* ptr_s = (int*)alloc((N_NODES+1)*sizeof(int));
  int* cur_r = (int*)alloc(N_NODES*sizeof(int));
  int* cur_s = (int*)alloc(N_NODES*sizeof(int));

  float* out_e = (float*)d_out;
  float* out_f = out_e + G_SEG;

  hipMemsetAsync(d_out, 0, (size_t)out_size*sizeof(float), stream);
  hipMemsetAsync(cnt_r, 0, N_NODES*sizeof(int), stream);
  hipMemsetAsync(cnt_s, 0, N_NODES*sizeof(int), stream);

  const int NB4 = N_NODES/4;
  const int EB  = N_EDGES/256;
  const int EB4 = N_EDGES/4;
  const int NBt = (N_NODES+255)/256;

  const float* Wup1 = Wup + KDIM*KDIM;
  const float* Wsc1 = Wsc + ZDIM*KDIM*KDIM;
  const float* Wout1 = Wout + 3*KDIM*KDIM;
  const float* theta1 = theta + 3*ZDIM*KDIM;
  const float* Wmix1 = Wmix + KDIM*KDIM;

  k_setup<<<153,256,0,stream>>>(We, Wup, Wsc, Wout, Wmix, Wr1, attrs, aE,
                                M0, Msc0, WoT0, WoT1, WmixT0, WupT1, P1, Qtab,
                                z_buf, e_node);
  k_table<<<TBINS+1,64,0,stream>>>(R1, R2, R3, R4, Ft2_0, Ft2_1, (float*)dF4);
  k_edge_setup<<<EB,256,0,stream>>>(pos, shifts, ei, z_buf, evec, emeta, cnt_r, cnt_s);
  k_scan<<<2,1024,0,stream>>>(cnt_r, ptr_r, cur_r, cnt_s, ptr_s, cur_s);
  k_fill<<<EB,256,0,stream>>>(emeta, cur_r, cur_s, pr_pack, ps_pack);

  // ---- forward ----
  k_layer0_fwd<<<NB4,256,0,stream>>>(z_buf, ptr_r, pr_pack, Ft2_0, M0,
      Wout, theta, Wmix, Msc0, w_read0, Wup1, Wsc1,
      A00, h1, sc1, e_node);
  k_layer1_fwd_bwd<<<NB4,256,0,stream>>>(z_buf, ptr_r, pr_pack, Ft2_1, h1,
      Wout1, theta1, Wmix1, sc1, Wr1, Wr2,
      P1, Qtab, WoT1, w_read0,
      gAr2, gF1, e_node);
  k_energy<<<NBt,256,0,stream>>>(e_node, batch, out_e);

  // ---- backward ----
  k_bwd_gH0<<<NB4,256,0,stream>>>(z_buf, ptr_s, ps_pack, Ft2_1, gAr2, WupT1, gF1,
      A00, WmixT0, WoT0, theta, gAr2);
  k_gr<<<EB4,256,0,stream>>>(emeta, dF4, gAr2, h1, M0, evec);
  k_force<<<N_NODES/16,256,0,stream>>>(ptr_r, pr_pack, ptr_s, ps_pack, evec, out_f);
}